// Round 5
// baseline (165.379 us; speedup 1.0000x reference)
//
#include <hip/hip_runtime.h>

static constexpr float EPSF = 1e-6f;

// Coefficient table, float4 k-pair packed, lane-coherent:
//   C4[(set*3+ch)*512 + kk*32 + ln] = { p[2kk], sn[2kk], p[2kk+1], sn[2kk+1] }
// where p_k = 1/denom_k, sn_k = -c*_k for solve-line ln.
// Sets 0..5  : x-direction, t = 0.1*set,          dt = DT/2 = 0.05
// Sets 6..10 : y-direction, t = 0.1*(set-6)+0.05, dt = DT   = 0.10

__global__ __launch_bounds__(64) void coef_kernel(
    const float* __restrict__ alpha_base, const float* __restrict__ beta_base,
    const float* __restrict__ alpha_tc,   const float* __restrict__ beta_tc,
    float4* __restrict__ C4)
{
    int gid  = blockIdx.x * 64 + threadIdx.x;
    int pair = gid >> 5;          // (set,ch) index, 0..32
    int ln   = gid & 31;
    if (pair >= 33) return;
    int set = pair / 3;
    int ch  = pair % 3;
    bool isX = (set < 6);
    float t  = isX ? 0.1f * (float)set : 0.1f * (float)(set - 6) + 0.05f;
    float dt = isX ? 0.05f : 0.1f;

    const float* bp; const float* tp; int stride;
    if (isX) { bp = alpha_base + (ch * 32 + ln) * 32; tp = alpha_tc + (ch * 32 + ln) * 32; stride = 1; }
    else     { bp = beta_base  + ch * 1024 + ln;      tp = beta_tc  + ch * 1024 + ln;      stride = 32; }

    float c[32];
    #pragma unroll
    for (int i = 0; i < 32; ++i)
        c[i] = fmaxf(fmaf(tp[i * stride], t, bp[i * stride]), EPSF);

    // replicate-pad 3-tap mean, scaled by dt (dh = 1)
    float cs[32];
    #pragma unroll
    for (int i = 0; i < 32; ++i) {
        float l = (i == 0)  ? c[0]  : c[i - 1];
        float r = (i == 31) ? c[31] : c[i + 1];
        cs[i] = (l + c[i] + r) / 3.0f * dt;
    }

    // Thomas coefficient recurrence: b_i = 1+2cs_i (ends 1+cs), a_i = c_i = -cs_i, a_0 := 0
    float p[32], sn[32];
    {
        float den = (1.0f + cs[0]) + EPSF;
        p[0]  = 1.0f / den;
        sn[0] = cs[0] * p[0];
        float sprev = -sn[0];
        #pragma unroll
        for (int i = 1; i < 32; ++i) {
            float bi = (i == 31) ? (1.0f + cs[31]) : fmaf(2.0f, cs[i], 1.0f);
            float ai = -cs[i];
            float dd = (bi - ai * sprev) + EPSF;
            float pi = 1.0f / dd;
            p[i]  = pi;
            float si = ai * pi;
            sn[i] = -si;
            sprev = si;
        }
    }

    float4* o = C4 + (set * 3 + ch) * 512 + ln;
    #pragma unroll
    for (int kk = 0; kk < 16; ++kk)
        o[kk * 32] = make_float4(p[2 * kk], sn[2 * kk], p[2 * kk + 1], sn[2 * kk + 1]);
}

// Batch-load one coefficient set into registers: 16 lane-coherent dwordx4.
__device__ __forceinline__ void loadc4(float p[32], float sn[32],
                                       const float4* __restrict__ c)
{
    #pragma unroll
    for (int kk = 0; kk < 16; ++kk) {
        float4 v = c[kk * 32];
        p[2 * kk]      = v.x; sn[2 * kk]     = v.y;
        p[2 * kk + 1]  = v.z; sn[2 * kk + 1] = v.w;
    }
}

// Dual-slab register Thomas solve: d[i] = {slabA, slabB}, shared coefficients.
// Two interleaved chains -> 2-way ILP in the serial recurrence.
__device__ __forceinline__ void solve2(float2 d[32], const float p[32], const float sn[32])
{
    float2 prev;
    prev.x = d[0].x * p[0];
    prev.y = d[0].y * p[0];
    d[0] = prev;
    #pragma unroll
    for (int i = 1; i < 32; ++i) {
        prev.x = fmaf(sn[i], prev.x, d[i].x * p[i]);
        prev.y = fmaf(sn[i], prev.y, d[i].y * p[i]);
        d[i] = prev;
    }
    #pragma unroll
    for (int i = 30; i >= 0; --i) {
        d[i].x = fmaf(sn[i], d[i + 1].x, d[i].x);
        d[i].y = fmaf(sn[i], d[i + 1].y, d[i].y);
    }
}

// ---------------------------------------------------------------------------
// Main kernel: 128 threads = 2 waves; each wave owns 2 slab-PAIRS end-to-end
// (zero barriers). LDS cell = float2{A,B}: rows are b128, cols sequential b64.
// Coefs double-buffered in regs: A-buffer = x-sets, B-buffer = y-sets, each
// load overlaps the other buffer's solve + transpose.
// ---------------------------------------------------------------------------
__global__ __launch_bounds__(128, 2) void diff_kernel(
    const float* __restrict__ u_in, float* __restrict__ u_out,
    const float4* __restrict__ C4, int blocksPerCh)
{
    __shared__ float4 tile4[4 * 544];   // 4 pairs x 32 rows x 17 float4 = 34816 B
    float2* tile2 = reinterpret_cast<float2*>(tile4);

    const int tid = threadIdx.x;        // 0..127
    const int bid = blockIdx.x;
    const int ch  = bid / blocksPerCh;
    const int b0  = (bid % blocksPerCh) * 8;
    const int w   = tid >> 6;           // wave 0..1
    const int l   = tid & 63;
    const int lp  = (w << 1) + (l >> 5);  // local pair 0..3
    const int ln  = l & 31;               // line index

    const int bA = b0 + lp * 2;           // batches (bA, bA+1) share this thread
    const float4* gA = reinterpret_cast<const float4*>(u_in + (bA * 3 + ch) * 1024);
    const float4* gB = gA + 768;          // next batch, same ch (3072 floats on)

    const float4* cb = C4 + ch * 512 + ln;   // + set*1536
    float pA[32], snA[32], pB[32], snB[32];
    loadc4(pA, snA, cb);                  // x set 0
    __builtin_amdgcn_sched_barrier(0);

    // ---- stage both slabs, interleaved into float2 cells ----
    const int srow = ln >> 3, schk = ln & 7;
    float4* tp4 = tile4 + lp * 544;
    float2* tp2 = tile2 + lp * 1088;
    #pragma unroll
    for (int r = 0; r < 8; ++r) {
        const int row = r * 4 + srow;
        float4 a = gA[row * 8 + schk];
        float4 b = gB[row * 8 + schk];
        tp4[row * 17 + 2 * schk]     = make_float4(a.x, b.x, a.y, b.y);
        tp4[row * 17 + 2 * schk + 1] = make_float4(a.z, b.z, a.w, b.w);
    }
    loadc4(pB, snB, cb + 6 * 1536);       // y set 6 (hidden under staging+solve)
    __builtin_amdgcn_sched_barrier(0);

    float2 d[32];
    #pragma unroll
    for (int j = 0; j < 16; ++j) {        // read row ln (b128)
        float4 v = tp4[ln * 17 + j];
        d[2 * j]     = make_float2(v.x, v.y);
        d[2 * j + 1] = make_float2(v.z, v.w);
    }
    solve2(d, pA, snA);                   // X, set 0

    const float4* cx = cb + 1 * 1536;     // x sets 1..5
    const float4* cy = cb + 7 * 1536;     // y sets 7..10

    for (int step = 0; step < 5; ++step) {
        loadc4(pA, snA, cx); cx += 1536;  // x set step+1; A freed by last X-solve
        __builtin_amdgcn_sched_barrier(0);
        #pragma unroll
        for (int j = 0; j < 16; ++j)      // write rows (b128)
            tp4[ln * 17 + j] = make_float4(d[2 * j].x, d[2 * j].y,
                                           d[2 * j + 1].x, d[2 * j + 1].y);
        #pragma unroll
        for (int i = 0; i < 32; ++i)      // read cols (sequential b64)
            d[i] = tp2[i * 34 + ln];
        solve2(d, pB, snB);               // Y, set 6+step

        if (step < 4) {
            loadc4(pB, snB, cy); cy += 1536;  // y set 7+step; B just freed
            __builtin_amdgcn_sched_barrier(0);
        }
        #pragma unroll
        for (int i = 0; i < 32; ++i)      // write cols (b64)
            tp2[i * 34 + ln] = d[i];
        #pragma unroll
        for (int j = 0; j < 16; ++j) {    // read rows (b128)
            float4 v = tp4[ln * 17 + j];
            d[2 * j]     = make_float2(v.x, v.y);
            d[2 * j + 1] = make_float2(v.z, v.w);
        }
        solve2(d, pA, snA);               // X (xb of step == xa of step+1)
        if (step < 4) solve2(d, pA, snA);
    }

    // ---- writeback: rows -> LDS, de-interleave, coalesced float4 out ----
    #pragma unroll
    for (int j = 0; j < 16; ++j)
        tp4[ln * 17 + j] = make_float4(d[2 * j].x, d[2 * j].y,
                                       d[2 * j + 1].x, d[2 * j + 1].y);
    float4* oA = reinterpret_cast<float4*>(u_out + (bA * 3 + ch) * 1024);
    float4* oB = oA + 768;
    #pragma unroll
    for (int r = 0; r < 8; ++r) {
        const int row = r * 4 + srow;
        float4 c0 = tp4[row * 17 + 2 * schk];
        float4 c1 = tp4[row * 17 + 2 * schk + 1];
        oA[row * 8 + schk] = make_float4(c0.x, c0.z, c1.x, c1.z);
        oB[row * 8 + schk] = make_float4(c0.y, c0.w, c1.y, c1.w);
    }
}

extern "C" void kernel_launch(void* const* d_in, const int* in_sizes, int n_in,
                              void* d_out, int out_size, void* d_ws, size_t ws_size,
                              hipStream_t stream)
{
    const float* u   = (const float*)d_in[0];
    const float* ab  = (const float*)d_in[1];
    const float* bb  = (const float*)d_in[2];
    const float* atc = (const float*)d_in[3];
    const float* btc = (const float*)d_in[4];
    float* out = (float*)d_out;
    float4* C4 = (float4*)d_ws;          // 33*512 float4 = 270336 B

    const int B = in_sizes[0] / (3 * 32 * 32);   // 2048
    const int blocksPerCh = B / 8;               // 256 (8 batches per block)

    coef_kernel<<<17, 64, 0, stream>>>(ab, bb, atc, btc, C4);
    diff_kernel<<<3 * blocksPerCh, 128, 0, stream>>>(u, out, C4, blocksPerCh);
}

// Round 6
// 116.890 us; speedup vs baseline: 1.4148x; 1.4148x over previous
//
#include <hip/hip_runtime.h>

static constexpr float EPSF = 1e-6f;

// Coefficient table, float2-interleaved, lane-coherent for the main kernel:
//   C2[(set*3+ch)*1024 + k*32 + ln] = { p_k = 1/denom_k,  sn_k = -c*_k }
// Sets 0..5  : x-direction, t = 0.1*set,          dt = DT/2 = 0.05
// Sets 6..10 : y-direction, t = 0.1*(set-6)+0.05, dt = DT   = 0.10

__global__ __launch_bounds__(64) void coef_kernel(
    const float* __restrict__ alpha_base, const float* __restrict__ beta_base,
    const float* __restrict__ alpha_tc,   const float* __restrict__ beta_tc,
    float2* __restrict__ C2)
{
    int gid  = blockIdx.x * 64 + threadIdx.x;
    int pair = gid >> 5;          // (set,ch) pair, 0..32
    int ln   = gid & 31;
    if (pair >= 33) return;
    int set = pair / 3;
    int ch  = pair % 3;
    bool isX = (set < 6);
    float t  = isX ? 0.1f * (float)set : 0.1f * (float)(set - 6) + 0.05f;
    float dt = isX ? 0.05f : 0.1f;

    const float* bp; const float* tp; int stride;
    if (isX) { bp = alpha_base + (ch * 32 + ln) * 32; tp = alpha_tc + (ch * 32 + ln) * 32; stride = 1; }
    else     { bp = beta_base  + ch * 1024 + ln;      tp = beta_tc  + ch * 1024 + ln;      stride = 32; }

    float c[32];
    #pragma unroll
    for (int i = 0; i < 32; ++i)
        c[i] = fmaxf(fmaf(tp[i * stride], t, bp[i * stride]), EPSF);

    float cs[32];
    #pragma unroll
    for (int i = 0; i < 32; ++i) {
        float l = (i == 0)  ? c[0]  : c[i - 1];
        float r = (i == 31) ? c[31] : c[i + 1];
        cs[i] = (l + c[i] + r) / 3.0f * dt;
    }

    // Thomas coefficient recurrence: b_i = 1+2cs_i (ends 1+cs), a_i = c_i = -cs_i, a_0 := 0
    float p[32], sn[32];
    {
        float den = (1.0f + cs[0]) + EPSF;
        p[0]  = 1.0f / den;
        sn[0] = cs[0] * p[0];
        float sprev = -sn[0];
        #pragma unroll
        for (int i = 1; i < 32; ++i) {
            float bi = (i == 31) ? (1.0f + cs[31]) : fmaf(2.0f, cs[i], 1.0f);
            float ai = -cs[i];
            float dd = (bi - ai * sprev) + EPSF;
            float pi = 1.0f / dd;
            p[i]  = pi;
            float si = ai * pi;
            sn[i] = -si;
            sprev = si;
        }
    }

    float2* o = C2 + (set * 3 + ch) * 1024 + ln;
    #pragma unroll
    for (int k = 0; k < 32; ++k) o[k * 32] = make_float2(p[k], sn[k]);
}

// Batch-load coefficients into registers (lane-coherent dwordx2; lanes 32-63
// mirror lanes 0-31 -> broadcast within the cache line).
__device__ __forceinline__ void loadc(float p[32], float sn[32],
                                      const float2* __restrict__ c)
{
    #pragma unroll
    for (int k = 0; k < 32; ++k) { float2 v = c[k * 32]; p[k] = v.x; sn[k] = v.y; }
}

// Pure-VALU register Thomas solve (coefs already in registers).
__device__ __forceinline__ void solve_reg(float d[32], const float p[32], const float sn[32])
{
    float prev = d[0] * p[0];
    d[0] = prev;
    #pragma unroll
    for (int i = 1; i < 32; ++i) {
        prev = fmaf(sn[i], prev, d[i] * p[i]);   // 4-cyc chain; mul independent
        d[i] = prev;
    }
    #pragma unroll
    for (int i = 30; i >= 0; --i)
        d[i] = fmaf(sn[i], d[i + 1], d[i]);
}

// ---------------------------------------------------------------------------
// Main kernel: ONE WAVE per block, owning 2 slabs in 8.5 KB LDS.
// 3072 single-wave blocks -> ~12 resident waves/CU, no barriers at all,
// no block-granularity tail. Tile stride 34: rows b64, cols conflict-free b32.
// ---------------------------------------------------------------------------
__global__ __launch_bounds__(64, 4) void diff_kernel(
    const float* __restrict__ u_in, float* __restrict__ u_out,
    const float2* __restrict__ C2, int blocksPerCh)
{
    __shared__ float tile[2 * 1088];   // 2 slabs, 32 rows x stride 34 = 8704 B
    const int l   = threadIdx.x;       // 0..63
    const int bid = blockIdx.x;
    const int ch  = bid / blocksPerCh;
    const int b0  = (bid % blocksPerCh) * 2;
    const int ls  = l >> 5;            // local slab 0..1
    const int ln  = l & 31;            // line index

    const float2* cb = C2 + ch * 1024 + ln;
    float p[32], sn[32];
    loadc(p, sn, cb);                  // set 0 coefs in flight
    __builtin_amdgcn_sched_barrier(0);

    // ---- stage the 2 slabs (coalesced float4) ----
    #pragma unroll
    for (int j = 0; j < 8; ++j) {
        int q   = j * 64 + l;
        int sl  = q >> 8;              // 0..1
        int rem = q & 255;             // float4 index within slab
        const float4 v = reinterpret_cast<const float4*>(
            u_in + ((b0 + sl) * 3 + ch) * 1024)[rem];
        float* dst = &tile[sl * 1088 + (rem >> 3) * 34 + ((rem & 7) << 2)];
        *(float2*)(dst)     = make_float2(v.x, v.y);
        *(float2*)(dst + 2) = make_float2(v.z, v.w);
    }

    float* tb = &tile[ls * 1088];
    float d[32];
    #pragma unroll
    for (int j = 0; j < 16; ++j) {
        float2 v = *(const float2*)(tb + ln * 34 + 2 * j);
        d[2 * j] = v.x; d[2 * j + 1] = v.y;
    }
    solve_reg(d, p, sn);               // x half-step, set 0

    const float2* cy = cb + 6 * 3072;  // y sets 6..10
    const float2* cx = cb + 1 * 3072;  // x sets 1..5

    for (int step = 0; step < 5; ++step) {
        // ---- y full-step ----
        loadc(p, sn, cy); cy += 3072;
        __builtin_amdgcn_sched_barrier(0);
        #pragma unroll
        for (int j = 0; j < 16; ++j)   // write rows (b64)
            *(float2*)(tb + ln * 34 + 2 * j) = make_float2(d[2 * j], d[2 * j + 1]);
        #pragma unroll
        for (int i = 0; i < 32; ++i)   // read columns (conflict-free b32)
            d[i] = tb[i * 34 + ln];
        solve_reg(d, p, sn);

        // ---- x half-step pair (sets step+1, shared coefs) ----
        loadc(p, sn, cx); cx += 3072;
        __builtin_amdgcn_sched_barrier(0);
        #pragma unroll
        for (int i = 0; i < 32; ++i)   // write columns
            tb[i * 34 + ln] = d[i];
        #pragma unroll
        for (int j = 0; j < 16; ++j) { // read rows (b64)
            float2 v = *(const float2*)(tb + ln * 34 + 2 * j);
            d[2 * j] = v.x; d[2 * j + 1] = v.y;
        }
        solve_reg(d, p, sn);
        if (step < 4) solve_reg(d, p, sn);
    }

    // ---- writeback (rows -> LDS, coalesced float4 out) ----
    #pragma unroll
    for (int j = 0; j < 16; ++j)
        *(float2*)(tb + ln * 34 + 2 * j) = make_float2(d[2 * j], d[2 * j + 1]);
    #pragma unroll
    for (int j = 0; j < 8; ++j) {
        int q   = j * 64 + l;
        int sl  = q >> 8;
        int rem = q & 255;
        const float* s_ = &tile[sl * 1088 + (rem >> 3) * 34 + ((rem & 7) << 2)];
        float4 v; v.x = s_[0]; v.y = s_[1]; v.z = s_[2]; v.w = s_[3];
        reinterpret_cast<float4*>(u_out + ((b0 + sl) * 3 + ch) * 1024)[rem] = v;
    }
}

extern "C" void kernel_launch(void* const* d_in, const int* in_sizes, int n_in,
                              void* d_out, int out_size, void* d_ws, size_t ws_size,
                              hipStream_t stream)
{
    const float* u   = (const float*)d_in[0];
    const float* ab  = (const float*)d_in[1];
    const float* bb  = (const float*)d_in[2];
    const float* atc = (const float*)d_in[3];
    const float* btc = (const float*)d_in[4];
    float* out = (float*)d_out;
    float2* C2 = (float2*)d_ws;        // 33*1024 float2 = 270336 B

    const int B = in_sizes[0] / (3 * 32 * 32);   // 2048
    const int blocksPerCh = B / 2;               // 1024 (2 slabs per 1-wave block)

    coef_kernel<<<17, 64, 0, stream>>>(ab, bb, atc, btc, C2);
    diff_kernel<<<3 * blocksPerCh, 64, 0, stream>>>(u, out, C2, blocksPerCh);
}

// Round 9
// 102.031 us; speedup vs baseline: 1.6209x; 1.1456x over previous
//
#include <hip/hip_runtime.h>

static constexpr float EPSF = 1e-6f;

// Coefficient table, float4 k-pair packed, lane-coherent:
//   C4[(set*3+ch)*512 + kk*32 + ln] = { p[2kk], sn[2kk], p[2kk+1], sn[2kk+1] }
// p_k = 1/denom_k, sn_k = -c*_k for solve-line ln.
// Sets 0..5  : x-direction, t = 0.1*set,          dt = DT/2 = 0.05
// Sets 6..10 : y-direction, t = 0.1*(set-6)+0.05, dt = DT   = 0.10

__global__ __launch_bounds__(64) void coef_kernel(
    const float* __restrict__ alpha_base, const float* __restrict__ beta_base,
    const float* __restrict__ alpha_tc,   const float* __restrict__ beta_tc,
    float4* __restrict__ C4)
{
    int gid  = blockIdx.x * 64 + threadIdx.x;
    int pair = gid >> 5;          // (set,ch) index, 0..32
    int ln   = gid & 31;
    if (pair >= 33) return;
    int set = pair / 3;
    int ch  = pair % 3;
    bool isX = (set < 6);
    float t  = isX ? 0.1f * (float)set : 0.1f * (float)(set - 6) + 0.05f;
    float dt = isX ? 0.05f : 0.1f;

    const float* bp; const float* tp; int stride;
    if (isX) { bp = alpha_base + (ch * 32 + ln) * 32; tp = alpha_tc + (ch * 32 + ln) * 32; stride = 1; }
    else     { bp = beta_base  + ch * 1024 + ln;      tp = beta_tc  + ch * 1024 + ln;      stride = 32; }

    float c[32];
    #pragma unroll
    for (int i = 0; i < 32; ++i)
        c[i] = fmaxf(fmaf(tp[i * stride], t, bp[i * stride]), EPSF);

    // replicate-pad 3-tap mean, scaled by dt (dh = 1)
    float cs[32];
    #pragma unroll
    for (int i = 0; i < 32; ++i) {
        float l = (i == 0)  ? c[0]  : c[i - 1];
        float r = (i == 31) ? c[31] : c[i + 1];
        cs[i] = (l + c[i] + r) / 3.0f * dt;
    }

    // Thomas coefficient recurrence: b_i = 1+2cs_i (ends 1+cs), a_i = c_i = -cs_i, a_0 := 0
    float p[32], sn[32];
    {
        float den = (1.0f + cs[0]) + EPSF;
        p[0]  = 1.0f / den;
        sn[0] = cs[0] * p[0];
        float sprev = -sn[0];
        #pragma unroll
        for (int i = 1; i < 32; ++i) {
            float bi = (i == 31) ? (1.0f + cs[31]) : fmaf(2.0f, cs[i], 1.0f);
            float ai = -cs[i];
            float dd = (bi - ai * sprev) + EPSF;
            float pi = 1.0f / dd;
            p[i]  = pi;
            float si = ai * pi;
            sn[i] = -si;
            sprev = si;
        }
    }

    float4* o = C4 + (set * 3 + ch) * 512 + ln;
    #pragma unroll
    for (int kk = 0; kk < 16; ++kk)
        o[kk * 32] = make_float4(p[2 * kk], sn[2 * kk], p[2 * kk + 1], sn[2 * kk + 1]);
}

// Batch-load one coefficient set: 16 lane-coherent dwordx4 (no deps).
__device__ __forceinline__ void loadc4(float p[32], float sn[32],
                                       const float4* __restrict__ c)
{
    #pragma unroll
    for (int kk = 0; kk < 16; ++kk) {
        float4 v = c[kk * 32];
        p[2 * kk]      = v.x; sn[2 * kk]     = v.y;
        p[2 * kk + 1]  = v.z; sn[2 * kk + 1] = v.w;
    }
}

// Dual-slab register Thomas solve: d[i] = {slabA, slabB}, shared coefficients.
// Two interleaved chains -> 2-way ILP in the serial recurrence.
__device__ __forceinline__ void solve2(float2 d[32], const float p[32], const float sn[32])
{
    float2 prev;
    prev.x = d[0].x * p[0];
    prev.y = d[0].y * p[0];
    d[0] = prev;
    #pragma unroll
    for (int i = 1; i < 32; ++i) {
        prev.x = fmaf(sn[i], prev.x, d[i].x * p[i]);
        prev.y = fmaf(sn[i], prev.y, d[i].y * p[i]);
        d[i] = prev;
    }
    #pragma unroll
    for (int i = 30; i >= 0; --i) {
        d[i].x = fmaf(sn[i], d[i + 1].x, d[i].x);
        d[i].y = fmaf(sn[i], d[i + 1].y, d[i].y);
    }
}

// ---------------------------------------------------------------------------
// Main kernel: ONE WAVE per block, 2 half-waves x 1 slab-PAIR each (4 slabs).
// LDS cell = float2{A,B}. Row = 32 cells = 16 float4, row stride 17 float4
// (34 float2) -> rows b128, cols b64: LDS instrs per slab HALVED vs
// one-slab-per-thread. Zero barriers (all wave-local).
// __launch_bounds__(64,1): no VGPR cap pressure -> no spill (round-5 lesson).
// ---------------------------------------------------------------------------
__global__ __launch_bounds__(64, 1) void diff_kernel(
    const float* __restrict__ u_in, float* __restrict__ u_out,
    const float4* __restrict__ C4, int blocksPerCh)
{
    __shared__ float4 tile4[2 * 546];   // 2 pairs x (32 rows x 17 float4 + 2 pad)
    const int l   = threadIdx.x;        // 0..63
    const int bid = blockIdx.x;
    const int ch  = bid / blocksPerCh;
    const int b0  = (bid % blocksPerCh) * 4;
    const int h   = l >> 5;             // pair index 0..1
    const int ln  = l & 31;             // line index

    const int bA = b0 + h * 2;          // this half-wave's batches (bA, bA+1)
    const float4* gA = reinterpret_cast<const float4*>(u_in + (bA * 3 + ch) * 1024);
    const float4* gB = gA + 768;        // next batch, same ch (3072 floats on)
    float4* T4 = tile4 + h * 546;
    float2* T2 = reinterpret_cast<float2*>(T4);

    const float4* cb = C4 + ch * 512 + ln;   // + set*1536
    float p[32], sn[32];
    loadc4(p, sn, cb);                  // x set 0 in flight
    __builtin_amdgcn_sched_barrier(0);

    // ---- stage both slabs, interleaved into float2 cells (all b128) ----
    const int srow = ln >> 3, schk = ln & 7;
    #pragma unroll
    for (int r = 0; r < 8; ++r) {
        const int row = r * 4 + srow;
        float4 a = gA[row * 8 + schk];
        float4 b = gB[row * 8 + schk];
        float4* dst = T4 + row * 17 + 2 * schk;
        dst[0] = make_float4(a.x, b.x, a.y, b.y);
        dst[1] = make_float4(a.z, b.z, a.w, b.w);
    }

    float2 d[32];
    #pragma unroll
    for (int j = 0; j < 16; ++j) {      // read row ln (b128)
        float4 v = T4[ln * 17 + j];
        d[2 * j]     = make_float2(v.x, v.y);
        d[2 * j + 1] = make_float2(v.z, v.w);
    }
    solve2(d, p, sn);                   // X, set 0

    const float4* cy = cb + 6 * 1536;   // y sets 6..10
    const float4* cx = cb + 1 * 1536;   // x sets 1..5

    for (int step = 0; step < 5; ++step) {
        // ---- y full-step ----
        loadc4(p, sn, cy); cy += 1536;
        __builtin_amdgcn_sched_barrier(0);
        #pragma unroll
        for (int j = 0; j < 16; ++j)    // write rows (b128)
            T4[ln * 17 + j] =
                make_float4(d[2 * j].x, d[2 * j].y, d[2 * j + 1].x, d[2 * j + 1].y);
        #pragma unroll
        for (int i = 0; i < 32; ++i)    // read cols (b64)
            d[i] = T2[i * 34 + ln];
        solve2(d, p, sn);               // Y, set 6+step

        // ---- x half-step pair (set step+1, shared coefs) ----
        loadc4(p, sn, cx); cx += 1536;
        __builtin_amdgcn_sched_barrier(0);
        #pragma unroll
        for (int i = 0; i < 32; ++i)    // write cols (b64)
            T2[i * 34 + ln] = d[i];
        #pragma unroll
        for (int j = 0; j < 16; ++j) {  // read rows (b128)
            float4 v = T4[ln * 17 + j];
            d[2 * j]     = make_float2(v.x, v.y);
            d[2 * j + 1] = make_float2(v.z, v.w);
        }
        solve2(d, p, sn);               // xb(step) == xa(step+1): same set
        if (step < 4) solve2(d, p, sn);
    }

    // ---- writeback: rows -> LDS (b128), de-interleave, coalesced out ----
    #pragma unroll
    for (int j = 0; j < 16; ++j)
        T4[ln * 17 + j] =
            make_float4(d[2 * j].x, d[2 * j].y, d[2 * j + 1].x, d[2 * j + 1].y);
    float4* oA = reinterpret_cast<float4*>(u_out + (bA * 3 + ch) * 1024);
    float4* oB = oA + 768;
    #pragma unroll
    for (int r = 0; r < 8; ++r) {
        const int row = r * 4 + srow;
        const float4* src = T4 + row * 17 + 2 * schk;
        float4 c0 = src[0], c1 = src[1];
        oA[row * 8 + schk] = make_float4(c0.x, c0.z, c1.x, c1.z);
        oB[row * 8 + schk] = make_float4(c0.y, c0.w, c1.y, c1.w);
    }
}

extern "C" void kernel_launch(void* const* d_in, const int* in_sizes, int n_in,
                              void* d_out, int out_size, void* d_ws, size_t ws_size,
                              hipStream_t stream)
{
    const float* u   = (const float*)d_in[0];
    const float* ab  = (const float*)d_in[1];
    const float* bb  = (const float*)d_in[2];
    const float* atc = (const float*)d_in[3];
    const float* btc = (const float*)d_in[4];
    float* out = (float*)d_out;
    float4* C4 = (float4*)d_ws;          // 33*512 float4 = 270336 B

    const int B = in_sizes[0] / (3 * 32 * 32);   // 2048
    const int blocksPerCh = B / 4;               // 512 (4 batches per 1-wave block)

    coef_kernel<<<17, 64, 0, stream>>>(ab, bb, atc, btc, C4);
    diff_kernel<<<3 * blocksPerCh, 64, 0, stream>>>(u, out, C4, blocksPerCh);
}